// Round 6
// baseline (780.589 us; speedup 1.0000x reference)
//
#include <hip/hip_runtime.h>
#include <stdint.h>
#include <math.h>

typedef unsigned long long u64;
typedef unsigned int u32;

#define NPI   360000
#define B_IMG 8
#define PRE   1000
#define POST  300
#define CAP   4096
#define NMSF  0.7f
#define IMG_W 800.0f
#define IMG_H 800.0f

#define NBIN    8192          // 13-bit sortable-key histogram
#define KSHIFT  19            // fkey >> 19 -> 13-bit bin
#define CHUNK_H 36            // hist blocks per image (divides 90000)
#define F4PB_H  (NPI / 4 / CHUNK_H)   // 2500
#define CHUNK_C 48            // compact blocks per image
#define F4PB_C  (NPI / 4 / CHUNK_C)   // 1875
#define EPB_C   (NPI / CHUNK_C)       // 7500
#define LBUF    1024          // per-block candidate buffer

// ---- workspace layout (bytes) ----
#define CNT_OFF    0          // 8*4
#define THRESH_OFF 128        // 8*4
#define BHIST_OFF  2048       // 8*36*8192*2 = 4718592 -> 4720640
#define CAND_OFF   4720640    // 8*4096*8 = 262144     -> 4982784
#define MASK_OFF   4982784    // 8*1000*16*8 = 1024000 -> 6006784

__device__ __forceinline__ u32 fkey(float f) {
  u32 u = __float_as_uint(f);
  return (u & 0x80000000u) ? ~u : (u | 0x80000000u);  // ascending-order bits
}
__device__ __forceinline__ u64 rl64(u64 v, int lane) {
  u32 lo = (u32)__builtin_amdgcn_readlane((int)(u32)v, lane);
  u32 hi = (u32)__builtin_amdgcn_readlane((int)(u32)(v >> 32), lane);
  return ((u64)hi << 32) | lo;
}
__device__ __forceinline__ u64 sx64(u64 v, int m) {
  u32 lo = (u32)__shfl_xor((int)(u32)v, m, 64);
  u32 hi = (u32)__shfl_xor((int)(u32)(v >> 32), m, 64);
  return ((u64)hi << 32) | lo;
}

// ---- K1: per-(image,chunk) 13-bit histogram, no global atomics ----
__global__ __launch_bounds__(256) void k_hist(const float* __restrict__ logits,
                                              u32* __restrict__ bhist) {
  __shared__ u32 h[NBIN];
  const int img = blockIdx.y, c = blockIdx.x;
  for (int i = threadIdx.x; i < NBIN; i += 256) h[i] = 0;
  __syncthreads();
  const float4* L = (const float4*)(logits + (size_t)img * NPI) + (size_t)c * F4PB_H;
  for (int i = threadIdx.x; i < F4PB_H; i += 256) {
    float4 v = L[i];
    atomicAdd(&h[fkey(v.x) >> KSHIFT], 1u);
    atomicAdd(&h[fkey(v.y) >> KSHIFT], 1u);
    atomicAdd(&h[fkey(v.z) >> KSHIFT], 1u);
    atomicAdd(&h[fkey(v.w) >> KSHIFT], 1u);
  }
  __syncthreads();
  u32* O = bhist + (size_t)(img * CHUNK_H + c) * (NBIN / 2);
  for (int i = threadIdx.x; i < NBIN / 2; i += 256)
    O[i] = (h[2 * i] & 0xFFFFu) | (h[2 * i + 1] << 16);
}

// ---- K2: fused reduce + threshold select (parallel suffix scan); zero cnt ----
__global__ __launch_bounds__(1024) void k_thresh(const u32* __restrict__ bhist,
                                                 int* __restrict__ thresh,
                                                 u32* __restrict__ cnt) {
  const int img = blockIdx.x;
  const int t = threadIdx.x;            // owns bins [8t, 8t+8)
  const int lane = t & 63, w = t >> 6;  // 16 waves
  u32 binc[8];
#pragma unroll
  for (int b = 0; b < 8; b++) binc[b] = 0;
  for (int c = 0; c < CHUNK_H; c++) {
    uint4 v = ((const uint4*)(bhist + (size_t)(img * CHUNK_H + c) * (NBIN / 2)))[t];
    binc[0] += v.x & 0xFFFFu; binc[1] += v.x >> 16;
    binc[2] += v.y & 0xFFFFu; binc[3] += v.y >> 16;
    binc[4] += v.z & 0xFFFFu; binc[5] += v.z >> 16;
    binc[6] += v.w & 0xFFFFu; binc[7] += v.w >> 16;
  }
  u32 s = 0;
#pragma unroll
  for (int b = 0; b < 8; b++) s += binc[b];
  // wave-level inclusive suffix sum (lane l -> sum over lanes >= l)
  u32 suf = s;
#pragma unroll
  for (int off = 1; off < 64; off <<= 1) {
    u32 o = (u32)__shfl_down((int)suf, off, 64);
    if (lane + off < 64) suf += o;
  }
  __shared__ u32 wtot[16];
  if (lane == 0) wtot[w] = suf;         // whole-wave total
  __syncthreads();
  u32 wsuf = 0;
  for (int ww = w + 1; ww < 16; ww++) wsuf += wtot[ww];
  u32 suffix_incl = suf + wsuf;         // count over groups >= t
  u32 s_excl = suffix_incl - s;         // count over groups > t
  if (suffix_incl >= (u32)PRE && s_excl < (u32)PRE) {
    u32 cum = s_excl;
    int bin = 8 * t;
#pragma unroll
    for (int b = 7; b >= 0; b--) {
      cum += binc[b];
      if (cum >= (u32)PRE) { bin = 8 * t + b; break; }
    }
    thresh[img] = bin;
  }
  if (img == 0 && t < 8) cnt[t] = 0;
}

// ---- K3: compact candidates >= threshold bin; one global atomic per block ----
__global__ __launch_bounds__(256) void k_compact(const float* __restrict__ logits,
                                                 const int* __restrict__ thresh,
                                                 u32* __restrict__ cnt,
                                                 u64* __restrict__ cand) {
  __shared__ u64 buf[LBUF];
  __shared__ u32 bcnt;
  __shared__ u32 gbase;
  const int img = blockIdx.y, c = blockIdx.x;
  const int tb  = thresh[img];
  if (threadIdx.x == 0) bcnt = 0;
  __syncthreads();
  const float4* L = (const float4*)(logits + (size_t)img * NPI) + (size_t)c * F4PB_C;
  const int ebase = c * EPB_C;
  for (int i = threadIdx.x; i < F4PB_C; i += 256) {
    float4 v = L[i];
    float xs[4] = {v.x, v.y, v.z, v.w};
#pragma unroll
    for (int q = 0; q < 4; q++) {
      float x = xs[q];
      if ((int)(fkey(x) >> KSHIFT) >= tb) {
        // fp32 sigmoid with correctly-rounded exp: replicates numpy f32
        // tie structure exactly (verified: absmax 0.0)
        float ef = (float)exp(-(double)x);
        float sg = 1.0f / (1.0f + ef);
        u32 e = (u32)(ebase + 4 * i + q);
        u32 p = atomicAdd(&bcnt, 1u);
        if (p < LBUF)
          buf[p] = ((u64)fkey(sg) << 32) | (u64)(0xFFFFFFFFu - e);
      }
    }
  }
  __syncthreads();
  if (threadIdx.x == 0) {
    u32 m = bcnt < LBUF ? bcnt : LBUF;
    bcnt = m;
    gbase = atomicAdd(&cnt[img], m);
  }
  __syncthreads();
  const u32 m = bcnt, gb = gbase;
  for (u32 j = threadIdx.x; j < m; j += 256) {
    u32 pos = gb + j;
    if (pos < CAP) cand[img * CAP + pos] = buf[j];
  }
}

// ---- K4: fused rank + decode + IoU + greedy NMS, one block per image ----
__global__ __launch_bounds__(1024) void k_mega(
    const float* __restrict__ deltas, const float* __restrict__ anchors,
    const u32* __restrict__ cnt, const u64* __restrict__ cand,
    u64* __restrict__ mask, float* __restrict__ out) {
  __shared__ u64 skey[CAP];           // 32 KB
  __shared__ float4 sbox[1024];       // 16 KB
  __shared__ float sarea[1024];       // 4 KB
  __shared__ float sscore[1024];      // 4 KB
  __shared__ u64 svalid[16];
  __shared__ int skeeplist[POST];
  __shared__ int skept;
  const int img = blockIdx.x;
  const int tid = threadIdx.x;
  u64* M = mask + (size_t)img * PRE * 16;

  int n = (int)cnt[img];
  if (n > CAP) n = CAP;
  // init LDS + load keys (0-key pads rank >= n, never emitted)
  sbox[tid] = make_float4(0.f, 0.f, 0.f, 0.f);
  sarea[tid] = 0.f; sscore[tid] = 0.f;
  if (tid < 16) svalid[tid] = 0ull;
#pragma unroll
  for (int r = 0; r < CAP / 1024; r++) {
    int i = tid + r * 1024;
    skey[i] = (i < n) ? cand[img * CAP + i] : 0ull;
  }
  __syncthreads();

  // ---- rank: count keys greater (keys unique: idx embedded) ----
  u64 kr[CAP / 1024];
  int cr[CAP / 1024];
#pragma unroll
  for (int r = 0; r < CAP / 1024; r++) { kr[r] = skey[tid + r * 1024]; cr[r] = 0; }
  const int nn = (n + 1) & ~1;
  for (int j = 0; j < nn; j += 2) {
    u64 kj0 = skey[j], kj1 = skey[j + 1];   // same addr all lanes -> broadcast
#pragma unroll
    for (int r = 0; r < CAP / 1024; r++) {
      cr[r] += (kj0 > kr[r]);
      cr[r] += (kj1 > kr[r]);
    }
  }
  // ---- decode top-PRE into LDS ----
#pragma unroll
  for (int r = 0; r < CAP / 1024; r++) {
    int row = tid + r * 1024;
    int rk = cr[r];
    if (row < n && rk < PRE) {
      u64 key = kr[r];
      u32 hi  = (u32)(key >> 32);
      u32 idx = 0xFFFFFFFFu - (u32)(key & 0xFFFFFFFFu);
      u32 su  = (hi & 0x80000000u) ? (hi ^ 0x80000000u) : ~hi;
      float sc = __uint_as_float(su);
      size_t off = (size_t)img * NPI + idx;
      float4 d = ((const float4*)deltas)[off];
      float4 a = ((const float4*)anchors)[off];
      float aw = a.z - a.x, ah = a.w - a.y;
      float acx = a.x + 0.5f * aw, acy = a.y + 0.5f * ah;
      float cx = d.x * aw + acx, cy = d.y * ah + acy;
      float w = expf(d.z) * aw, h = expf(d.w) * ah;
      float x1 = cx - 0.5f * w, y1 = cy - 0.5f * h;
      float x2 = cx + 0.5f * w, y2 = cy + 0.5f * h;
      x1 = fminf(fmaxf(x1, 0.f), IMG_W);
      y1 = fminf(fmaxf(y1, 0.f), IMG_H);
      x2 = fminf(fmaxf(x2, 0.f), IMG_W);
      y2 = fminf(fmaxf(y2, 0.f), IMG_H);
      sbox[rk]  = make_float4(x1, y1, x2, y2);
      sarea[rk] = (x2 - x1) * (y2 - y1);
      sscore[rk] = sc;
      if (((x2 - x1) >= 1e-3f) && ((y2 - y1) >= 1e-3f))
        atomicOr(&svalid[rk >> 6], 1ull << (rk & 63));
    }
  }
  __syncthreads();

  // ---- IoU mask: wave wv = word, lane = row-in-chunk; broadcast inner reads ----
  {
    const int lane = tid & 63;
    const int wv   = tid >> 6;
    const int cbase = wv << 6;
    int rem = PRE - cbase;
    u64 tmask = (rem >= 64) ? ~0ull : ((rem <= 0) ? 0ull : ((1ull << rem) - 1ull));
#pragma unroll
    for (int rc = 0; rc < 16; rc++) {
      int i = rc * 64 + lane;
      float4 bi = sbox[i];
      float  ai = sarea[i];
      u64 bits = 0;
#pragma unroll
      for (int k = 0; k < 64; k++) {
        float4 bc = sbox[cbase + k];   // broadcast read
        float ac  = sarea[cbase + k];
        float ltx = fmaxf(bi.x, bc.x), lty = fmaxf(bi.y, bc.y);
        float rbx = fminf(bi.z, bc.z), rby = fminf(bi.w, bc.w);
        float iw = fmaxf(rbx - ltx, 0.f), ih = fmaxf(rby - lty, 0.f);
        float inter = iw * ih;
        float iou = inter / (ai + ac - inter + 1e-9f);  // IEEE div, matches ref
        bits |= (iou > NMSF) ? (1ull << k) : 0ull;
      }
      int d = i - cbase;
      u64 gtmask = (d < 0) ? ~0ull : ((d >= 63) ? 0ull : (~0ull << (d + 1)));
      bits &= gtmask & tmask;
      if (i < PRE) M[(size_t)i * 16 + wv] = bits;
    }
  }
  __syncthreads();   // mask visible block-wide (L2-hot reads below)

  // ---- greedy scan: wave 0, diag in registers, readlane decisions ----
  if (tid < 64) {
    const int lane = tid;
    u64 diag[16];
#pragma unroll
    for (int cc = 0; cc < 16; cc++) {
      int row = cc * 64 + lane;
      diag[cc] = (row < PRE) ? M[(size_t)row * 16 + cc] : 0ull;
    }
    const int w = lane & 15, g = lane >> 4;
    u64 rem = ~0ull;
    if (lane < 16) {
      rem = ~svalid[lane];
      if (lane == 15) rem |= 0xFFFFFF0000000000ull;  // rows 1000..1023 invalid
    }
    int kept = 0;
#pragma unroll
    for (int cc = 0; cc < 16; cc++) {
      u64 alive = ~rl64(rem, cc);      // wave-uniform
      int kept0 = kept;
      while (alive != 0ull && kept < POST) {
        int r = __builtin_ctzll(alive);
        if (lane == 0) skeeplist[kept] = cc * 64 + r;
        kept++;
        u64 sup = rl64(diag[cc], r);   // row's in-chunk suppression word
        alive &= ~sup;
        alive &= ~(1ull << r);
      }
      int nc = kept - kept0;
      if (nc > 0 && kept < POST && cc < 15) {
        // batch-OR kept rows' full mask rows into rem (off the serial chain)
        u64 part = 0;
        for (int j = g; j < nc; j += 4) {
          int row = skeeplist[kept0 + j];
          part |= M[(size_t)row * 16 + w];   // L2-hot
        }
        part |= sx64(part, 16);
        part |= sx64(part, 32);
        rem |= part;                   // only lanes <16 meaningful
      }
      if (kept >= POST) break;
    }
    if (lane == 0) skept = kept;
  }
  __syncthreads();

  // ---- output 300 rows from LDS ----
  if (tid < POST) {
    float4 bx = make_float4(0.f, 0.f, 0.f, 0.f);
    float  sc = 0.f;
    if (tid < skept) {
      int i = skeeplist[tid];
      bx = sbox[i];
      sc = sscore[i];
    }
    float* o = out + ((size_t)img * POST + tid) * 5;
    o[0] = bx.x; o[1] = bx.y; o[2] = bx.z; o[3] = bx.w; o[4] = sc;
  }
}

extern "C" void kernel_launch(void* const* d_in, const int* in_sizes, int n_in,
                              void* d_out, int out_size, void* d_ws, size_t ws_size,
                              hipStream_t stream) {
  const float* logits  = (const float*)d_in[0];
  const float* deltas  = (const float*)d_in[1];
  const float* anchors = (const float*)d_in[2];
  float* out = (float*)d_out;
  char* ws = (char*)d_ws;

  u32* cnt    = (u32*)(ws + CNT_OFF);
  int* thresh = (int*)(ws + THRESH_OFF);
  u32* bhist  = (u32*)(ws + BHIST_OFF);
  u64* cand   = (u64*)(ws + CAND_OFF);
  u64* mask   = (u64*)(ws + MASK_OFF);

  dim3 gh(CHUNK_H, B_IMG);
  k_hist<<<gh, 256, 0, stream>>>(logits, bhist);
  k_thresh<<<B_IMG, 1024, 0, stream>>>(bhist, thresh, cnt);
  dim3 gc(CHUNK_C, B_IMG);
  k_compact<<<gc, 256, 0, stream>>>(logits, thresh, cnt, cand);
  k_mega<<<B_IMG, 1024, 0, stream>>>(deltas, anchors, cnt, cand, mask, out);
}

// Round 7
// 212.411 us; speedup vs baseline: 3.6749x; 3.6749x over previous
//
#include <hip/hip_runtime.h>
#include <stdint.h>
#include <math.h>

typedef unsigned long long u64;
typedef unsigned int u32;

#define NPI   360000
#define B_IMG 8
#define PRE   1000
#define POST  300
#define CAP   4096
#define NMSF  0.7f
#define IMG_W 800.0f
#define IMG_H 800.0f

#define NBIN    8192          // 13-bit sortable-key histogram
#define KSHIFT  19            // fkey >> 19 -> 13-bit bin
#define CHUNK_H 36            // hist blocks per image (divides 90000)
#define F4PB_H  (NPI / 4 / CHUNK_H)   // 2500
#define CHUNK_C 48            // compact blocks per image
#define F4PB_C  (NPI / 4 / CHUNK_C)   // 1875
#define EPB_C   (NPI / CHUNK_C)       // 7500
#define LBUF    1024          // per-block candidate buffer

// ---- workspace layout (bytes) ----
#define CNT_OFF    0          // 8*4
#define THRESH_OFF 128        // 8*4
#define VALID_OFF  256        // 8*16*8 = 1024       -> 1280
#define BOX_OFF    2048       // 8*1000*16 = 128000  -> 130048
#define SCORE_OFF  130048     // 8*1000*4 = 32000    -> 162048
#define BHIST_OFF  163840     // 8*36*8192*2 = 4718592 -> 4882432
#define CAND_OFF   4882432    // 8*4096*8 = 262144   -> 5144576
#define MASK_OFF   5144576    // 8*1000*16*8 = 1024000 -> 6168576

__device__ __forceinline__ u32 fkey(float f) {
  u32 u = __float_as_uint(f);
  return (u & 0x80000000u) ? ~u : (u | 0x80000000u);  // ascending-order bits
}
__device__ __forceinline__ u64 rl64(u64 v, int lane) {
  u32 lo = (u32)__builtin_amdgcn_readlane((int)(u32)v, lane);
  u32 hi = (u32)__builtin_amdgcn_readlane((int)(u32)(v >> 32), lane);
  return ((u64)hi << 32) | lo;
}
__device__ __forceinline__ u64 sx64(u64 v, int m) {
  u32 lo = (u32)__shfl_xor((int)(u32)v, m, 64);
  u32 hi = (u32)__shfl_xor((int)(u32)(v >> 32), m, 64);
  return ((u64)hi << 32) | lo;
}

// ---- K1: per-(image,chunk) 13-bit histogram, no global atomics ----
__global__ __launch_bounds__(256) void k_hist(const float* __restrict__ logits,
                                              u32* __restrict__ bhist) {
  __shared__ u32 h[NBIN];
  const int img = blockIdx.y, c = blockIdx.x;
  for (int i = threadIdx.x; i < NBIN; i += 256) h[i] = 0;
  __syncthreads();
  const float4* L = (const float4*)(logits + (size_t)img * NPI) + (size_t)c * F4PB_H;
  for (int i = threadIdx.x; i < F4PB_H; i += 256) {
    float4 v = L[i];
    atomicAdd(&h[fkey(v.x) >> KSHIFT], 1u);
    atomicAdd(&h[fkey(v.y) >> KSHIFT], 1u);
    atomicAdd(&h[fkey(v.z) >> KSHIFT], 1u);
    atomicAdd(&h[fkey(v.w) >> KSHIFT], 1u);
  }
  __syncthreads();
  u32* O = bhist + (size_t)(img * CHUNK_H + c) * (NBIN / 2);
  for (int i = threadIdx.x; i < NBIN / 2; i += 256)
    O[i] = (h[2 * i] & 0xFFFFu) | (h[2 * i + 1] << 16);
}

// ---- K2: fused reduce + threshold select (parallel suffix scan); zero cnt/validw ----
__global__ __launch_bounds__(1024) void k_thresh(const u32* __restrict__ bhist,
                                                 int* __restrict__ thresh,
                                                 u32* __restrict__ cnt,
                                                 u64* __restrict__ validw) {
  const int img = blockIdx.x;
  const int t = threadIdx.x;            // owns bins [8t, 8t+8)
  const int lane = t & 63, w = t >> 6;  // 16 waves
  u32 binc[8];
#pragma unroll
  for (int b = 0; b < 8; b++) binc[b] = 0;
  for (int c = 0; c < CHUNK_H; c++) {
    uint4 v = ((const uint4*)(bhist + (size_t)(img * CHUNK_H + c) * (NBIN / 2)))[t];
    binc[0] += v.x & 0xFFFFu; binc[1] += v.x >> 16;
    binc[2] += v.y & 0xFFFFu; binc[3] += v.y >> 16;
    binc[4] += v.z & 0xFFFFu; binc[5] += v.z >> 16;
    binc[6] += v.w & 0xFFFFu; binc[7] += v.w >> 16;
  }
  u32 s = 0;
#pragma unroll
  for (int b = 0; b < 8; b++) s += binc[b];
  // wave-level inclusive suffix sum (lane l -> sum over lanes >= l)
  u32 suf = s;
#pragma unroll
  for (int off = 1; off < 64; off <<= 1) {
    u32 o = (u32)__shfl_down((int)suf, off, 64);
    if (lane + off < 64) suf += o;
  }
  __shared__ u32 wtot[16];
  if (lane == 0) wtot[w] = suf;         // whole-wave total
  __syncthreads();
  u32 wsuf = 0;
  for (int ww = w + 1; ww < 16; ww++) wsuf += wtot[ww];
  u32 suffix_incl = suf + wsuf;         // count over groups >= t
  u32 s_excl = suffix_incl - s;         // count over groups > t
  if (suffix_incl >= (u32)PRE && s_excl < (u32)PRE) {
    u32 cum = s_excl;
    int bin = 8 * t;
#pragma unroll
    for (int b = 7; b >= 0; b--) {
      cum += binc[b];
      if (cum >= (u32)PRE) { bin = 8 * t + b; break; }
    }
    thresh[img] = bin;
  }
  if (img == 0) {
    if (t < 8) cnt[t] = 0;
    if (t < 128) validw[t] = 0ull;
  }
}

// ---- K3: compact candidates >= threshold bin; one global atomic per block ----
__global__ __launch_bounds__(256) void k_compact(const float* __restrict__ logits,
                                                 const int* __restrict__ thresh,
                                                 u32* __restrict__ cnt,
                                                 u64* __restrict__ cand) {
  __shared__ u64 buf[LBUF];
  __shared__ u32 bcnt;
  __shared__ u32 gbase;
  const int img = blockIdx.y, c = blockIdx.x;
  const int tb  = thresh[img];
  if (threadIdx.x == 0) bcnt = 0;
  __syncthreads();
  const float4* L = (const float4*)(logits + (size_t)img * NPI) + (size_t)c * F4PB_C;
  const int ebase = c * EPB_C;
  for (int i = threadIdx.x; i < F4PB_C; i += 256) {
    float4 v = L[i];
    float xs[4] = {v.x, v.y, v.z, v.w};
#pragma unroll
    for (int q = 0; q < 4; q++) {
      float x = xs[q];
      if ((int)(fkey(x) >> KSHIFT) >= tb) {
        // fp32 sigmoid with correctly-rounded exp: replicates numpy f32
        // tie structure exactly (verified: absmax 0.0)
        float ef = (float)exp(-(double)x);
        float sg = 1.0f / (1.0f + ef);
        u32 e = (u32)(ebase + 4 * i + q);
        u32 p = atomicAdd(&bcnt, 1u);
        if (p < LBUF)
          buf[p] = ((u64)fkey(sg) << 32) | (u64)(0xFFFFFFFFu - e);
      }
    }
  }
  __syncthreads();
  if (threadIdx.x == 0) {
    u32 m = bcnt < LBUF ? bcnt : LBUF;
    bcnt = m;
    gbase = atomicAdd(&cnt[img], m);
  }
  __syncthreads();
  const u32 m = bcnt, gb = gbase;
  for (u32 j = threadIdx.x; j < m; j += 256) {
    u32 pos = gb + j;
    if (pos < CAP) cand[img * CAP + pos] = buf[j];
  }
}

// ---- K4: exact rank (keys unique: idx embedded) + decode/clip, no sort ----
#define RB 8
__device__ __forceinline__ void emit_row(
    int img, int row, u64 key,
    const float* __restrict__ deltas, const float* __restrict__ anchors,
    float4* __restrict__ boxes, float* __restrict__ scores, u64* __restrict__ validw) {
  u32 hi  = (u32)(key >> 32);
  u32 idx = 0xFFFFFFFFu - (u32)(key & 0xFFFFFFFFu);
  u32 su  = (hi & 0x80000000u) ? (hi ^ 0x80000000u) : ~hi;
  float sc = __uint_as_float(su);
  size_t off = (size_t)img * NPI + idx;
  float4 d = ((const float4*)deltas)[off];
  float4 a = ((const float4*)anchors)[off];
  float aw = a.z - a.x, ah = a.w - a.y;
  float acx = a.x + 0.5f * aw, acy = a.y + 0.5f * ah;
  float cx = d.x * aw + acx, cy = d.y * ah + acy;
  float w = expf(d.z) * aw, h = expf(d.w) * ah;
  float x1 = cx - 0.5f * w, y1 = cy - 0.5f * h;
  float x2 = cx + 0.5f * w, y2 = cy + 0.5f * h;
  x1 = fminf(fmaxf(x1, 0.f), IMG_W);
  y1 = fminf(fmaxf(y1, 0.f), IMG_H);
  x2 = fminf(fmaxf(x2, 0.f), IMG_W);
  y2 = fminf(fmaxf(y2, 0.f), IMG_H);
  boxes[img * PRE + row]  = make_float4(x1, y1, x2, y2);
  scores[img * PRE + row] = sc;
  if (((x2 - x1) >= 1e-3f) && ((y2 - y1) >= 1e-3f))
    atomicOr(&validw[img * 16 + (row >> 6)], 1ull << (row & 63));
}

__global__ __launch_bounds__(256) void k_rank(
    const float* __restrict__ deltas, const float* __restrict__ anchors,
    const u32* __restrict__ cnt, const u64* __restrict__ cand,
    float4* __restrict__ boxes, float* __restrict__ scores, u64* __restrict__ validw) {
  __shared__ u64 skey[CAP];
  const int img = blockIdx.y;
  int n = (int)cnt[img];
  if (n > CAP) n = CAP;
  for (int i = threadIdx.x; i < n; i += 256) skey[i] = cand[img * CAP + i];
  __syncthreads();
  const int r0 = blockIdx.x * 256 + threadIdx.x;
  const int r1 = r0 + RB * 256;
  u64 k0 = (r0 < n) ? skey[r0] : 0ull;
  u64 k1 = (r1 < n) ? skey[r1] : 0ull;
  int c0 = 0, c1 = 0;
  for (int j = 0; j < n; j++) {
    u64 kj = skey[j];           // same address across lanes -> LDS broadcast
    c0 += (kj > k0);
    c1 += (kj > k1);
  }
  if (r0 < n && c0 < PRE) emit_row(img, c0, k0, deltas, anchors, boxes, scores, validw);
  if (r1 < n && c1 < PRE) emit_row(img, c1, k1, deltas, anchors, boxes, scores, validw);
}

// ---- K5: suppression bitmask via LDS broadcast (zero bank conflicts) ----
// grid (16, B): block = 1024 thr = 16 waves; wave wv computes mask word wv
// for the block's 64 rows (lane = row). Inner read sb[c] is same-address
// across all 64 lanes -> broadcast. bit (i,c)=1 iff c>i && iou>thr.
__global__ __launch_bounds__(1024) void k_iou(const float4* __restrict__ boxes,
                                              u64* __restrict__ mask) {
  __shared__ float4 sb[1024];
  __shared__ float  sa[1024];
  const int img = blockIdx.y;
  const int tid = threadIdx.x;
  {
    float4 b = (tid < PRE) ? boxes[img * PRE + tid]
                           : make_float4(0.f, 0.f, 0.f, 0.f);
    sb[tid] = b;
    sa[tid] = (b.z - b.x) * (b.w - b.y);
  }
  __syncthreads();
  const int lane = tid & 63;
  const int wv   = tid >> 6;          // word index 0..15
  const int i    = blockIdx.x * 64 + lane;   // row
  const bool rowok = (i < PRE);
  const float4 bi = sb[blockIdx.x * 64 + lane];  // garbage for i>=PRE, masked later
  const float  ai = sa[blockIdx.x * 64 + lane];
  const int cbase = wv << 6;
  u64 bits = 0;
#pragma unroll
  for (int k = 0; k < 64; k++) {
    int c = cbase + k;
    float4 bc = sb[c];                // broadcast read
    float ac  = sa[c];
    float ltx = fmaxf(bi.x, bc.x), lty = fmaxf(bi.y, bc.y);
    float rbx = fminf(bi.z, bc.z), rby = fminf(bi.w, bc.w);
    float iw = fmaxf(rbx - ltx, 0.f), ih = fmaxf(rby - lty, 0.f);
    float inter = iw * ih;
    float iou = inter / (ai + ac - inter + 1e-9f);  // IEEE div, matches ref
    bits |= (iou > NMSF) ? (1ull << k) : 0ull;
  }
  // keep only c > i
  int d = i - cbase;
  u64 gtmask = (d < 0) ? ~0ull : ((d >= 63) ? 0ull : (~0ull << (d + 1)));
  // keep only c < PRE
  int rem = PRE - cbase;
  u64 tmask = (rem >= 64) ? ~0ull : ((rem <= 0) ? 0ull : ((1ull << rem) - 1ull));
  bits &= gtmask & tmask;
  if (rowok) mask[((size_t)img * PRE + i) * 16 + wv] = bits;
}

// ---- K6: chunked greedy scan — scalar in-chunk decisions via readlane ----
#define LDSROWS 496
#define NMS_T   320
__global__ __launch_bounds__(NMS_T) void k_nms(
    const u64* __restrict__ mask, const u64* __restrict__ validw,
    const float4* __restrict__ boxes, const float* __restrict__ scores,
    float* __restrict__ out) {
  __shared__ u64 smask[LDSROWS * 16];
  __shared__ int skeeplist[POST];
  __shared__ int skept;
  const int img = blockIdx.x;
  const int tid = threadIdx.x;
  const u64* M = mask + (size_t)img * PRE * 16;
  // wave0: diagonal 64x64 blocks -> registers (lane r holds row 64cc+r, word cc)
  u64 diag[16];
  if (tid < 64) {
#pragma unroll
    for (int cc = 0; cc < 16; cc++) {
      int row = cc * 64 + tid;
      diag[cc] = (row < PRE) ? M[(size_t)row * 16 + cc] : 0ull;
    }
  }
  for (int e = tid; e < LDSROWS * 16; e += NMS_T) smask[e] = M[e];
  __syncthreads();
  if (tid < 64) {
    const int lane = tid;
    const int w = lane & 15, g = lane >> 4;
    u64 rem = ~0ull;
    if (lane < 16) {
      rem = ~validw[img * 16 + lane];
      if (lane == 15) rem |= 0xFFFFFF0000000000ull;  // rows 1000..1023 invalid
    }
    int kept = 0;
#pragma unroll
    for (int cc = 0; cc < 16; cc++) {
      u64 alive = ~rl64(rem, cc);      // wave-uniform
      int kept0 = kept;
      while (alive != 0ull && kept < POST) {
        int r = __builtin_ctzll(alive);
        if (lane == 0) skeeplist[kept] = cc * 64 + r;
        kept++;
        u64 sup = rl64(diag[cc], r);   // row's in-chunk suppression word
        alive &= ~sup;
        alive &= ~(1ull << r);
      }
      int nc = kept - kept0;
      if (nc > 0 && kept < POST && cc < 15) {
        // batch-OR kept rows' full mask rows into rem (off the serial chain)
        u64 part = 0;
        for (int j = g; j < nc; j += 4) {
          int row = skeeplist[kept0 + j];
          part |= (row < LDSROWS) ? smask[row * 16 + w] : M[(size_t)row * 16 + w];
        }
        part |= sx64(part, 16);
        part |= sx64(part, 32);
        rem |= part;                   // only lanes <16 meaningful
      }
      if (kept >= POST) break;
    }
    if (lane == 0) skept = kept;
  }
  __syncthreads();
  if (tid < POST) {
    float4 bx = make_float4(0.f, 0.f, 0.f, 0.f);
    float  sc = 0.f;
    if (tid < skept) {
      int i = skeeplist[tid];
      bx = boxes[img * PRE + i];
      sc = scores[img * PRE + i];
    }
    float* o = out + ((size_t)img * POST + tid) * 5;
    o[0] = bx.x; o[1] = bx.y; o[2] = bx.z; o[3] = bx.w; o[4] = sc;
  }
}

extern "C" void kernel_launch(void* const* d_in, const int* in_sizes, int n_in,
                              void* d_out, int out_size, void* d_ws, size_t ws_size,
                              hipStream_t stream) {
  const float* logits  = (const float*)d_in[0];
  const float* deltas  = (const float*)d_in[1];
  const float* anchors = (const float*)d_in[2];
  float* out = (float*)d_out;
  char* ws = (char*)d_ws;

  u32* cnt      = (u32*)(ws + CNT_OFF);
  int* thresh   = (int*)(ws + THRESH_OFF);
  u64* validw   = (u64*)(ws + VALID_OFF);
  float4* boxes = (float4*)(ws + BOX_OFF);
  float* scores = (float*)(ws + SCORE_OFF);
  u32* bhist    = (u32*)(ws + BHIST_OFF);
  u64* cand     = (u64*)(ws + CAND_OFF);
  u64* mask     = (u64*)(ws + MASK_OFF);

  dim3 gh(CHUNK_H, B_IMG);
  k_hist<<<gh, 256, 0, stream>>>(logits, bhist);
  k_thresh<<<B_IMG, 1024, 0, stream>>>(bhist, thresh, cnt, validw);
  dim3 gc(CHUNK_C, B_IMG);
  k_compact<<<gc, 256, 0, stream>>>(logits, thresh, cnt, cand);
  dim3 gr(RB, B_IMG);
  k_rank<<<gr, 256, 0, stream>>>(deltas, anchors, cnt, cand, boxes, scores, validw);
  dim3 g2(16, B_IMG);
  k_iou<<<g2, 1024, 0, stream>>>(boxes, mask);
  k_nms<<<B_IMG, NMS_T, 0, stream>>>(mask, validw, boxes, scores, out);
}

// Round 8
// 210.199 us; speedup vs baseline: 3.7136x; 1.0105x over previous
//
#include <hip/hip_runtime.h>
#include <stdint.h>
#include <math.h>

typedef unsigned long long u64;
typedef unsigned int u32;

#define NPI   360000
#define B_IMG 8
#define PRE   1000
#define POST  300
#define CAP   4096
#define NMSF  0.7f
#define IMG_W 800.0f
#define IMG_H 800.0f

#define NBIN    8192          // 13-bit sortable-key histogram
#define KSHIFT  19            // fkey >> 19 -> 13-bit bin
#define CHUNK_H 36            // hist blocks per image (divides 90000)
#define F4PB_H  (NPI / 4 / CHUNK_H)   // 2500
#define CHUNK_C 48            // compact blocks per image
#define F4PB_C  (NPI / 4 / CHUNK_C)   // 1875
#define EPB_C   (NPI / CHUNK_C)       // 7500
#define LBUF    1024          // per-block candidate buffer

// ---- workspace layout (bytes) ----
#define CNT_OFF    0          // 8*4
#define THRESH_OFF 128        // 8*4
#define VALID_OFF  256        // 8*16*8 = 1024      -> 1280
#define RHIST_OFF  4096       // 8*8192*4 = 262144  -> 266240
#define ZERO_BYTES 266240     // cnt+thresh+validw+rhist zeroed each launch
#define BOX_OFF    266240     // 8*1000*16 = 128000 -> 394240
#define SCORE_OFF  394240     // 8*1000*4 = 32000   -> 426240
#define CAND_OFF   426240     // 8*4096*8 = 262144  -> 688384
#define MASK_OFF   688384     // 8*1000*16*8 = 1024000 -> 1712384

__device__ __forceinline__ u32 fkey(float f) {
  u32 u = __float_as_uint(f);
  return (u & 0x80000000u) ? ~u : (u | 0x80000000u);  // ascending-order bits
}
__device__ __forceinline__ u64 rl64(u64 v, int lane) {
  u32 lo = (u32)__builtin_amdgcn_readlane((int)(u32)v, lane);
  u32 hi = (u32)__builtin_amdgcn_readlane((int)(u32)(v >> 32), lane);
  return ((u64)hi << 32) | lo;
}
__device__ __forceinline__ u64 sx64(u64 v, int m) {
  u32 lo = (u32)__shfl_xor((int)(u32)v, m, 64);
  u32 hi = (u32)__shfl_xor((int)(u32)(v >> 32), m, 64);
  return ((u64)hi << 32) | lo;
}

// ---- K1: per-(image,chunk) LDS histogram; flush nonzero bins via global atomics ----
__global__ __launch_bounds__(256) void k_hist(const float* __restrict__ logits,
                                              u32* __restrict__ rhist) {
  __shared__ u32 h[NBIN];
  const int img = blockIdx.y, c = blockIdx.x;
  for (int i = threadIdx.x; i < NBIN; i += 256) h[i] = 0;
  __syncthreads();
  const float4* L = (const float4*)(logits + (size_t)img * NPI) + (size_t)c * F4PB_H;
  for (int i = threadIdx.x; i < F4PB_H; i += 256) {
    float4 v = L[i];
    atomicAdd(&h[fkey(v.x) >> KSHIFT], 1u);
    atomicAdd(&h[fkey(v.y) >> KSHIFT], 1u);
    atomicAdd(&h[fkey(v.z) >> KSHIFT], 1u);
    atomicAdd(&h[fkey(v.w) >> KSHIFT], 1u);
  }
  __syncthreads();
  u32* R = rhist + img * NBIN;
  for (int i = threadIdx.x; i < NBIN; i += 256) {
    u32 cn = h[i];
    if (cn) atomicAdd(&R[i], cn);       // ~1.2k hot bins/block, scattered
  }
}

// ---- K2: threshold select via parallel suffix scan over reduced hist ----
__global__ __launch_bounds__(1024) void k_select(const u32* __restrict__ rhist,
                                                 int* __restrict__ thresh) {
  const int img = blockIdx.x;
  const int t = threadIdx.x;            // owns bins [8t, 8t+8)
  const int lane = t & 63, w = t >> 6;  // 16 waves
  const uint4* H4 = (const uint4*)(rhist + img * NBIN);
  uint4 v0 = H4[2 * t], v1 = H4[2 * t + 1];
  u32 binc[8] = {v0.x, v0.y, v0.z, v0.w, v1.x, v1.y, v1.z, v1.w};
  u32 s = 0;
#pragma unroll
  for (int b = 0; b < 8; b++) s += binc[b];
  // wave-level inclusive suffix sum (lane l -> sum over lanes >= l)
  u32 suf = s;
#pragma unroll
  for (int off = 1; off < 64; off <<= 1) {
    u32 o = (u32)__shfl_down((int)suf, off, 64);
    if (lane + off < 64) suf += o;
  }
  __shared__ u32 wtot[16];
  if (lane == 0) wtot[w] = suf;         // whole-wave total
  __syncthreads();
  u32 wsuf = 0;
  for (int ww = w + 1; ww < 16; ww++) wsuf += wtot[ww];
  u32 suffix_incl = suf + wsuf;         // count over groups >= t
  u32 s_excl = suffix_incl - s;         // count over groups > t
  if (suffix_incl >= (u32)PRE && s_excl < (u32)PRE) {
    u32 cum = s_excl;
    int bin = 8 * t;
#pragma unroll
    for (int b = 7; b >= 0; b--) {
      cum += binc[b];
      if (cum >= (u32)PRE) { bin = 8 * t + b; break; }
    }
    thresh[img] = bin;
  }
}

// ---- K3: compact candidates >= threshold bin; one global atomic per block ----
__global__ __launch_bounds__(256) void k_compact(const float* __restrict__ logits,
                                                 const int* __restrict__ thresh,
                                                 u32* __restrict__ cnt,
                                                 u64* __restrict__ cand) {
  __shared__ u64 buf[LBUF];
  __shared__ u32 bcnt;
  __shared__ u32 gbase;
  const int img = blockIdx.y, c = blockIdx.x;
  const int tb  = thresh[img];
  if (threadIdx.x == 0) bcnt = 0;
  __syncthreads();
  const float4* L = (const float4*)(logits + (size_t)img * NPI) + (size_t)c * F4PB_C;
  const int ebase = c * EPB_C;
  for (int i = threadIdx.x; i < F4PB_C; i += 256) {
    float4 v = L[i];
    float xs[4] = {v.x, v.y, v.z, v.w};
#pragma unroll
    for (int q = 0; q < 4; q++) {
      float x = xs[q];
      if ((int)(fkey(x) >> KSHIFT) >= tb) {
        // fp32 sigmoid with correctly-rounded exp: replicates numpy f32
        // tie structure exactly (verified: absmax 0.0)
        float ef = (float)exp(-(double)x);
        float sg = 1.0f / (1.0f + ef);
        u32 e = (u32)(ebase + 4 * i + q);
        u32 p = atomicAdd(&bcnt, 1u);
        if (p < LBUF)
          buf[p] = ((u64)fkey(sg) << 32) | (u64)(0xFFFFFFFFu - e);
      }
    }
  }
  __syncthreads();
  if (threadIdx.x == 0) {
    u32 m = bcnt < LBUF ? bcnt : LBUF;
    bcnt = m;
    gbase = atomicAdd(&cnt[img], m);
  }
  __syncthreads();
  const u32 m = bcnt, gb = gbase;
  for (u32 j = threadIdx.x; j < m; j += 256) {
    u32 pos = gb + j;
    if (pos < CAP) cand[img * CAP + pos] = buf[j];
  }
}

// ---- K4: exact rank (keys unique: idx embedded) + decode/clip, no sort ----
#define RB 8
__device__ __forceinline__ void emit_row(
    int img, int row, u64 key,
    const float* __restrict__ deltas, const float* __restrict__ anchors,
    float4* __restrict__ boxes, float* __restrict__ scores, u64* __restrict__ validw) {
  u32 hi  = (u32)(key >> 32);
  u32 idx = 0xFFFFFFFFu - (u32)(key & 0xFFFFFFFFu);
  u32 su  = (hi & 0x80000000u) ? (hi ^ 0x80000000u) : ~hi;
  float sc = __uint_as_float(su);
  size_t off = (size_t)img * NPI + idx;
  float4 d = ((const float4*)deltas)[off];
  float4 a = ((const float4*)anchors)[off];
  float aw = a.z - a.x, ah = a.w - a.y;
  float acx = a.x + 0.5f * aw, acy = a.y + 0.5f * ah;
  float cx = d.x * aw + acx, cy = d.y * ah + acy;
  float w = expf(d.z) * aw, h = expf(d.w) * ah;
  float x1 = cx - 0.5f * w, y1 = cy - 0.5f * h;
  float x2 = cx + 0.5f * w, y2 = cy + 0.5f * h;
  x1 = fminf(fmaxf(x1, 0.f), IMG_W);
  y1 = fminf(fmaxf(y1, 0.f), IMG_H);
  x2 = fminf(fmaxf(x2, 0.f), IMG_W);
  y2 = fminf(fmaxf(y2, 0.f), IMG_H);
  boxes[img * PRE + row]  = make_float4(x1, y1, x2, y2);
  scores[img * PRE + row] = sc;
  if (((x2 - x1) >= 1e-3f) && ((y2 - y1) >= 1e-3f))
    atomicOr(&validw[img * 16 + (row >> 6)], 1ull << (row & 63));
}

__global__ __launch_bounds__(256) void k_rank(
    const float* __restrict__ deltas, const float* __restrict__ anchors,
    const u32* __restrict__ cnt, const u64* __restrict__ cand,
    float4* __restrict__ boxes, float* __restrict__ scores, u64* __restrict__ validw) {
  __shared__ u64 skey[CAP];
  const int img = blockIdx.y;
  int n = (int)cnt[img];
  if (n > CAP) n = CAP;
  for (int i = threadIdx.x; i < n; i += 256) skey[i] = cand[img * CAP + i];
  __syncthreads();
  const int r0 = blockIdx.x * 256 + threadIdx.x;
  const int r1 = r0 + RB * 256;
  u64 k0 = (r0 < n) ? skey[r0] : 0ull;
  u64 k1 = (r1 < n) ? skey[r1] : 0ull;
  int c0 = 0, c1 = 0;
  for (int j = 0; j < n; j++) {
    u64 kj = skey[j];           // same address across lanes -> LDS broadcast
    c0 += (kj > k0);
    c1 += (kj > k1);
  }
  if (r0 < n && c0 < PRE) emit_row(img, c0, k0, deltas, anchors, boxes, scores, validw);
  if (r1 < n && c1 < PRE) emit_row(img, c1, k1, deltas, anchors, boxes, scores, validw);
}

// ---- K5: suppression bitmask via LDS broadcast (zero bank conflicts) ----
__global__ __launch_bounds__(1024) void k_iou(const float4* __restrict__ boxes,
                                              u64* __restrict__ mask) {
  __shared__ float4 sb[1024];
  __shared__ float  sa[1024];
  const int img = blockIdx.y;
  const int tid = threadIdx.x;
  {
    float4 b = (tid < PRE) ? boxes[img * PRE + tid]
                           : make_float4(0.f, 0.f, 0.f, 0.f);
    sb[tid] = b;
    sa[tid] = (b.z - b.x) * (b.w - b.y);
  }
  __syncthreads();
  const int lane = tid & 63;
  const int wv   = tid >> 6;          // word index 0..15
  const int i    = blockIdx.x * 64 + lane;   // row
  const bool rowok = (i < PRE);
  const float4 bi = sb[blockIdx.x * 64 + lane];
  const float  ai = sa[blockIdx.x * 64 + lane];
  const int cbase = wv << 6;
  u64 bits = 0;
#pragma unroll
  for (int k = 0; k < 64; k++) {
    int c = cbase + k;
    float4 bc = sb[c];                // broadcast read
    float ac  = sa[c];
    float ltx = fmaxf(bi.x, bc.x), lty = fmaxf(bi.y, bc.y);
    float rbx = fminf(bi.z, bc.z), rby = fminf(bi.w, bc.w);
    float iw = fmaxf(rbx - ltx, 0.f), ih = fmaxf(rby - lty, 0.f);
    float inter = iw * ih;
    float iou = inter / (ai + ac - inter + 1e-9f);  // IEEE div, matches ref
    bits |= (iou > NMSF) ? (1ull << k) : 0ull;
  }
  int d = i - cbase;
  u64 gtmask = (d < 0) ? ~0ull : ((d >= 63) ? 0ull : (~0ull << (d + 1)));
  int rem = PRE - cbase;
  u64 tmask = (rem >= 64) ? ~0ull : ((rem <= 0) ? 0ull : ((1ull << rem) - 1ull));
  bits &= gtmask & tmask;
  if (rowok) mask[((size_t)img * PRE + i) * 16 + wv] = bits;
}

// ---- K6: chunked greedy scan — scalar in-chunk decisions via readlane ----
#define LDSROWS 496
#define NMS_T   320
__global__ __launch_bounds__(NMS_T) void k_nms(
    const u64* __restrict__ mask, const u64* __restrict__ validw,
    const float4* __restrict__ boxes, const float* __restrict__ scores,
    float* __restrict__ out) {
  __shared__ u64 smask[LDSROWS * 16];
  __shared__ int skeeplist[POST];
  __shared__ int skept;
  const int img = blockIdx.x;
  const int tid = threadIdx.x;
  const u64* M = mask + (size_t)img * PRE * 16;
  u64 diag[16];
  if (tid < 64) {
#pragma unroll
    for (int cc = 0; cc < 16; cc++) {
      int row = cc * 64 + tid;
      diag[cc] = (row < PRE) ? M[(size_t)row * 16 + cc] : 0ull;
    }
  }
  for (int e = tid; e < LDSROWS * 16; e += NMS_T) smask[e] = M[e];
  __syncthreads();
  if (tid < 64) {
    const int lane = tid;
    const int w = lane & 15, g = lane >> 4;
    u64 rem = ~0ull;
    if (lane < 16) {
      rem = ~validw[img * 16 + lane];
      if (lane == 15) rem |= 0xFFFFFF0000000000ull;  // rows 1000..1023 invalid
    }
    int kept = 0;
#pragma unroll
    for (int cc = 0; cc < 16; cc++) {
      u64 alive = ~rl64(rem, cc);      // wave-uniform
      int kept0 = kept;
      while (alive != 0ull && kept < POST) {
        int r = __builtin_ctzll(alive);
        if (lane == 0) skeeplist[kept] = cc * 64 + r;
        kept++;
        u64 sup = rl64(diag[cc], r);   // row's in-chunk suppression word
        alive &= ~sup;
        alive &= ~(1ull << r);
      }
      int nc = kept - kept0;
      if (nc > 0 && kept < POST && cc < 15) {
        u64 part = 0;
        for (int j = g; j < nc; j += 4) {
          int row = skeeplist[kept0 + j];
          part |= (row < LDSROWS) ? smask[row * 16 + w] : M[(size_t)row * 16 + w];
        }
        part |= sx64(part, 16);
        part |= sx64(part, 32);
        rem |= part;                   // only lanes <16 meaningful
      }
      if (kept >= POST) break;
    }
    if (lane == 0) skept = kept;
  }
  __syncthreads();
  if (tid < POST) {
    float4 bx = make_float4(0.f, 0.f, 0.f, 0.f);
    float  sc = 0.f;
    if (tid < skept) {
      int i = skeeplist[tid];
      bx = boxes[img * PRE + i];
      sc = scores[img * PRE + i];
    }
    float* o = out + ((size_t)img * POST + tid) * 5;
    o[0] = bx.x; o[1] = bx.y; o[2] = bx.z; o[3] = bx.w; o[4] = sc;
  }
}

extern "C" void kernel_launch(void* const* d_in, const int* in_sizes, int n_in,
                              void* d_out, int out_size, void* d_ws, size_t ws_size,
                              hipStream_t stream) {
  const float* logits  = (const float*)d_in[0];
  const float* deltas  = (const float*)d_in[1];
  const float* anchors = (const float*)d_in[2];
  float* out = (float*)d_out;
  char* ws = (char*)d_ws;

  u32* cnt      = (u32*)(ws + CNT_OFF);
  int* thresh   = (int*)(ws + THRESH_OFF);
  u64* validw   = (u64*)(ws + VALID_OFF);
  u32* rhist    = (u32*)(ws + RHIST_OFF);
  float4* boxes = (float4*)(ws + BOX_OFF);
  float* scores = (float*)(ws + SCORE_OFF);
  u64* cand     = (u64*)(ws + CAND_OFF);
  u64* mask     = (u64*)(ws + MASK_OFF);

  hipMemsetAsync(ws, 0, ZERO_BYTES, stream);   // cnt + validw + rhist
  dim3 gh(CHUNK_H, B_IMG);
  k_hist<<<gh, 256, 0, stream>>>(logits, rhist);
  k_select<<<B_IMG, 1024, 0, stream>>>(rhist, thresh);
  dim3 gc(CHUNK_C, B_IMG);
  k_compact<<<gc, 256, 0, stream>>>(logits, thresh, cnt, cand);
  dim3 gr(RB, B_IMG);
  k_rank<<<gr, 256, 0, stream>>>(deltas, anchors, cnt, cand, boxes, scores, validw);
  dim3 g2(16, B_IMG);
  k_iou<<<g2, 1024, 0, stream>>>(boxes, mask);
  k_nms<<<B_IMG, NMS_T, 0, stream>>>(mask, validw, boxes, scores, out);
}